// Round 7
// baseline (648.493 us; speedup 1.0000x reference)
//
#include <hip/hip_runtime.h>

// GQA forward: X@Wq/Wk/Wv -> RoPE -> causal flash attention -> @Wo
// B=2 S=2048 HID=2048 NH=16 NKV=4 HD=128 GROUPS=4

typedef __attribute__((ext_vector_type(8))) short bf16x8;
typedef __attribute__((ext_vector_type(4))) float f32x4;
typedef __attribute__((ext_vector_type(16))) float f32x16;
typedef __attribute__((ext_vector_type(4))) unsigned short u16x4;
typedef unsigned short u16;

#define B_   2
#define S_   2048
#define HID_ 2048
#define NH_  16
#define NKV_ 4
#define HD_  128

__device__ __forceinline__ u16 f2bf(float f) {
  unsigned u = __float_as_uint(f);
  u = (u + 0x7FFFu + ((u >> 16) & 1u)) >> 16;
  return (u16)u;
}
__device__ __forceinline__ float bf2f(u16 h) {
  return __uint_as_float(((unsigned)h) << 16);
}

__device__ __forceinline__ void gl_lds16(const void* g, void* l) {
  __builtin_amdgcn_global_load_lds(
      (const __attribute__((address_space(1))) void*)g,
      (__attribute__((address_space(3))) void*)l, 16, 0, 0);
}

// ---------------- fp32 -> bf16 conversion (vectorized, 8 elems/thread) ------
__global__ void convert_bf16(const float* __restrict__ src, u16* __restrict__ dst, int n8) {
  int i = blockIdx.x * 256 + threadIdx.x;
  if (i >= n8) return;
  const float4* s = (const float4*)src + (size_t)i * 2;
  float4 a = s[0], b = s[1];
  union { u16 u[8]; uint4 v; } o;
  o.u[0] = f2bf(a.x); o.u[1] = f2bf(a.y); o.u[2] = f2bf(a.z); o.u[3] = f2bf(a.w);
  o.u[4] = f2bf(b.x); o.u[5] = f2bf(b.y); o.u[6] = f2bf(b.z); o.u[7] = f2bf(b.w);
  ((uint4*)dst)[i] = o.v;
}

// ---------------- 128x128 bf16 GEMM, C = A @ B^T (m97 structure) -----------
template<int EPI>
__launch_bounds__(256, 2)
__global__ void gemm128(const u16* __restrict__ A, const u16* __restrict__ Bm,
                        float* __restrict__ C, u16* __restrict__ Qb,
                        u16* __restrict__ Kb, u16* __restrict__ Vb,
                        int N, int K)
{
  __shared__ u16 As[128 * 64];
  __shared__ u16 Bs[128 * 64];
  const int tid = threadIdx.x;
  const int lane = tid & 63;
  const int w = tid >> 6;
  const int lo = lane & 15, hi = lane >> 4;
  const int wr = w >> 1, wc = w & 1;
  const int rowA0 = blockIdx.x * 128;
  const int rowB0 = blockIdx.y * 128;

  f32x4 acc[4][4] = {};

  for (int kt = 0; kt < K; kt += 64) {
    __syncthreads();
#pragma unroll
    for (int it = 0; it < 4; ++it) {
      int c = it * 256 + tid;       // 16B chunk; row = c>>3, 8 chunks/row
      int r = c >> 3;
      int cb = (c & 7) * 8;
      gl_lds16(A + (size_t)(rowA0 + r) * K + kt + cb, (char*)As + c * 16);
      gl_lds16(Bm + (size_t)(rowB0 + r) * K + kt + cb, (char*)Bs + c * 16);
    }
    __syncthreads();
#pragma unroll
    for (int kk = 0; kk < 64; kk += 32) {
      bf16x8 af[4], bfr[4];
#pragma unroll
      for (int m = 0; m < 4; ++m)
        af[m] = *(const bf16x8*)(As + (wr * 64 + m * 16 + lo) * 64 + kk + hi * 8);
#pragma unroll
      for (int n = 0; n < 4; ++n)
        bfr[n] = *(const bf16x8*)(Bs + (wc * 64 + n * 16 + lo) * 64 + kk + hi * 8);
#pragma unroll
      for (int m = 0; m < 4; ++m)
#pragma unroll
        for (int n = 0; n < 4; ++n)
          acc[m][n] = __builtin_amdgcn_mfma_f32_16x16x32_bf16(af[m], bfr[n], acc[m][n], 0, 0, 0);
    }
  }

#pragma unroll
  for (int m = 0; m < 4; ++m) {
#pragma unroll
    for (int n = 0; n < 4; ++n) {
#pragma unroll
      for (int r = 0; r < 4; ++r) {
        int grow = rowA0 + wr * 64 + m * 16 + hi * 4 + r;
        int gcol = rowB0 + wc * 64 + n * 16 + lo;
        float v = acc[m][n][r];
        if (EPI == 0) {
          C[(size_t)grow * N + gcol] = v;
        } else {
          int bb = grow >> 11, s = grow & 2047;
          u16 hv = f2bf(v);
          if (gcol < 2048) {
            int h = gcol >> 7, d = gcol & 127;
            Qb[(((size_t)bb * NH_ + h) * S_ + s) * HD_ + d] = hv;
          } else if (gcol < 2560) {
            int h = (gcol - 2048) >> 7, d = gcol & 127;
            Kb[(((size_t)bb * NKV_ + h) * S_ + s) * HD_ + d] = hv;
          } else {
            int h = (gcol - 2560) >> 7, d = gcol & 127;
            Vb[(((size_t)bb * NKV_ + h) * S_ + s) * HD_ + d] = hv;
          }
        }
      }
    }
  }
}

// ---------------- in-place RoPE on Qb and Kb (bf16) -------------------------
__global__ void rope_k(u16* __restrict__ Qb, u16* __restrict__ Kb,
                       const float* __restrict__ fcos, const float* __restrict__ fsin)
{
  int idx = blockIdx.x * 256 + threadIdx.x;   // 40*2048*16 chunks total
  int chunk = idx & 15;
  int s = (idx >> 4) & 2047;
  int hs = idx >> 15;                          // 0..39
  u16* p = (hs < 32) ? (Qb + ((size_t)hs * S_ + s) * HD_ + chunk * 8)
                     : (Kb + ((size_t)(hs - 32) * S_ + s) * HD_ + chunk * 8);
  uint4 raw = *(uint4*)p;
  float4 c4 = *(const float4*)(fcos + (size_t)s * 64 + chunk * 4);
  float4 s4 = *(const float4*)(fsin + (size_t)s * 64 + chunk * 4);
  float cc[4] = {c4.x, c4.y, c4.z, c4.w};
  float ss[4] = {s4.x, s4.y, s4.z, s4.w};
  unsigned* rw = (unsigned*)&raw;
#pragma unroll
  for (int j = 0; j < 4; ++j) {
    float x0 = bf2f((u16)(rw[j] & 0xFFFFu));
    float x1 = bf2f((u16)(rw[j] >> 16));
    float o0 = x0 * cc[j] - x1 * ss[j];
    float o1 = x0 * ss[j] + x1 * cc[j];
    rw[j] = (unsigned)f2bf(o0) | ((unsigned)f2bf(o1) << 16);
  }
  *(uint4*)p = raw;
}

// ---------------- V transpose: Vb [hs][s][d] -> Vtg [hs][d][s] -------------
__global__ void transpose_v(const u16* __restrict__ Vb, u16* __restrict__ Vtg)
{
  __shared__ u16 t[64][65];
  const int st = blockIdx.x, dt = blockIdx.y, hs = blockIdx.z;
  const u16* src = Vb + ((size_t)hs * S_ + st * 64) * HD_ + dt * 64;
#pragma unroll
  for (int it = 0; it < 2; ++it) {
    int c = it * 256 + threadIdx.x;
    int r = c >> 3, cb = (c & 7) * 8;
    uint4 v = *(const uint4*)(src + (size_t)r * HD_ + cb);
    u16* u = (u16*)&v;
#pragma unroll
    for (int e = 0; e < 8; ++e) t[r][cb + e] = u[e];
  }
  __syncthreads();
#pragma unroll
  for (int it = 0; it < 2; ++it) {
    int c = it * 256 + threadIdx.x;
    int r2 = c >> 3, cb2 = (c & 7) * 8;
    union { u16 u[8]; uint4 v; } o;
#pragma unroll
    for (int e = 0; e < 8; ++e) o.u[e] = t[cb2 + e][r2];
    *(uint4*)(Vtg + ((size_t)hs * HD_ + dt * 64 + r2) * S_ + st * 64 + cb2) = o.v;
  }
}

// ---------------- causal flash attention (LDS-free, register-pipelined) -----
// L2-direct (KV is L2-resident), no LDS/barriers. R6 was latency-bound
// (MfmaUtil 9 / VALU 15 / Occ 15): K loads sat at the head of each tile's
// dependency chain. Fix: software pipeline in registers --
//   * K double-buffered (kA/kB, static banks, 2-phase alternation):
//     next tile's K issued right after current QK^T -> hidden under
//     softmax+PV (~600 cyc).
//   * V split: dt0-1 issued before softmax (hidden under mask/max/exp2),
//     dt2-3 issued after pb (hidden under PV dt0-1).
// 1 wave = one 32-row q-tile; waves {x, 63-x, 31-x, 32+x} per block
// (balanced); grid (16,NH,B) = 512 blocks x 4 waves = 2048 waves resident.
__launch_bounds__(256, 2)
__global__ void flash_attn(const u16* __restrict__ Qb, const u16* __restrict__ Kb,
                           const u16* __restrict__ Vtg, u16* __restrict__ AO)
{
  const int tid = threadIdx.x, lane = tid & 63, w = tid >> 6;
  const int ql = lane & 31, hh = lane >> 5;
  const int x = blockIdx.x, h = blockIdx.y, b = blockIdx.z, kvh = h >> 2;
  const u16* Qh = Qb + ((size_t)b * NH_ + h) * S_ * HD_;
  const u16* Kh = Kb + ((size_t)b * NKV_ + kvh) * S_ * HD_;
  const u16* Vh = Vtg + ((size_t)b * NKV_ + kvh) * HD_ * S_;
  const float cf = 0.12752704581383682f;  // (1/sqrt(128)) * log2(e)
  const float NEG = -30000.f;

  const int qt = (w == 0) ? x : (w == 1) ? (63 - x) : (w == 2) ? (31 - x) : (32 + x);
  const int q0 = qt * 32;
  const int qg = q0 + ql;               // this lane's q row
  const int nt = (qt >> 1) + 1;         // KV tiles of 64 rows

  bf16x8 qf[8];
#pragma unroll
  for (int s = 0; s < 8; ++s)
    qf[s] = *(const bf16x8*)(Qh + (size_t)qg * HD_ + s * 16 + hh * 8);

  f32x16 o[4] = {};
  float m = NEG, l = 0.f;

  bf16x8 kA[16], kB[16];

  auto loadK = [&](bf16x8 (&kd)[16], int t) {
    const u16* Kt = Kh + (size_t)(t * 64) * HD_;
#pragma unroll
    for (int sl = 0; sl < 8; ++sl) {
      kd[sl]     = *(const bf16x8*)(Kt + (size_t)ql * HD_ + sl * 16 + hh * 8);
      kd[8 + sl] = *(const bf16x8*)(Kt + (size_t)(32 + ql) * HD_ + sl * 16 + hh * 8);
    }
  };

  auto body = [&](bf16x8 (&kc)[16], bf16x8 (&kn)[16], int t) {
    const int kt = t * 64;

    // ---- QK^T: S^T[kv 64][q 32] with current K bank ----
    f32x16 st[2] = {};
    __builtin_amdgcn_s_setprio(1);
#pragma unroll
    for (int sl = 0; sl < 8; ++sl) {
      st[0] = __builtin_amdgcn_mfma_f32_32x32x16_bf16(kc[sl],     qf[sl], st[0], 0, 0, 0);
      st[1] = __builtin_amdgcn_mfma_f32_32x32x16_bf16(kc[8 + sl], qf[sl], st[1], 0, 0, 0);
    }
    __builtin_amdgcn_s_setprio(0);

    // ---- prefetch next K into the other bank (hides under softmax+PV) ----
    if (t + 1 < nt) loadK(kn, t + 1);

    // ---- prefetch V for dt=0,1 (hides under mask/max/exp2) ----
    bf16x8 vf0[8];
#pragma unroll
    for (int dt = 0; dt < 2; ++dt)
#pragma unroll
      for (int ks = 0; ks < 4; ++ks)
        vf0[4 * dt + ks] = *(const bf16x8*)(Vh + (size_t)(32 * dt + ql) * S_ + kt + ks * 16 + hh * 8);

    // ---- mask (only tiles touching the diagonal) ----
    if (kt + 63 > q0) {
#pragma unroll
      for (int i = 0; i < 2; ++i)
#pragma unroll
        for (int r = 0; r < 16; ++r) {
          int kv = kt + 32 * i + (r & 3) + 8 * (r >> 2) + 4 * hh;
          if (kv > qg) st[i][r] = NEG;
        }
    }

    // ---- row max: in-lane tree + cross-half shfl ----
    float mx[8];
#pragma unroll
    for (int r = 0; r < 8; ++r)
      mx[r] = fmaxf(fmaxf(st[0][r], st[0][r + 8]), fmaxf(st[1][r], st[1][r + 8]));
#pragma unroll
    for (int d = 4; d > 0; d >>= 1)
#pragma unroll
      for (int r = 0; r < d; ++r) mx[r] = fmaxf(mx[r], mx[r + d]);
    float tmax = fmaxf(mx[0], __shfl_xor(mx[0], 32));

    // ---- defer-max (T13): rescale only when max grew materially ----
    if (!__all((tmax - m) * cf <= 8.f)) {
      float mn = fmaxf(m, tmax);
      float rs = __builtin_exp2f((m - mn) * cf);
      m = mn; l *= rs;
#pragma unroll
      for (int dt = 0; dt < 4; ++dt)
#pragma unroll
        for (int r = 0; r < 16; ++r) o[dt][r] *= rs;
    }

    // ---- exp2 + row sum ----
    const float mc = m * cf;
#pragma unroll
    for (int i = 0; i < 2; ++i)
#pragma unroll
      for (int r = 0; r < 16; ++r)
        st[i][r] = __builtin_exp2f(__builtin_fmaf(st[i][r], cf, -mc));
    float sm[8];
#pragma unroll
    for (int r = 0; r < 8; ++r)
      sm[r] = (st[0][r] + st[0][r + 8]) + (st[1][r] + st[1][r + 8]);
#pragma unroll
    for (int d = 4; d > 0; d >>= 1)
#pragma unroll
      for (int r = 0; r < d; ++r) sm[r] += sm[r + d];
    l += sm[0] + __shfl_xor(sm[0], 32);

    // ---- P -> PV B-frag: cvt_pk + cross-half shfl exchange ----
    bf16x8 pb[4];
#pragma unroll
    for (int i = 0; i < 2; ++i)
#pragma unroll
      for (int s = 0; s < 2; ++s) {
        unsigned wA, wC, wB, wD;
        asm("v_cvt_pk_bf16_f32 %0, %1, %2" : "=v"(wA) : "v"(st[i][8*s+0]), "v"(st[i][8*s+1]));
        asm("v_cvt_pk_bf16_f32 %0, %1, %2" : "=v"(wC) : "v"(st[i][8*s+2]), "v"(st[i][8*s+3]));
        asm("v_cvt_pk_bf16_f32 %0, %1, %2" : "=v"(wB) : "v"(st[i][8*s+4]), "v"(st[i][8*s+5]));
        asm("v_cvt_pk_bf16_f32 %0, %1, %2" : "=v"(wD) : "v"(st[i][8*s+6]), "v"(st[i][8*s+7]));
        unsigned tA = (unsigned)__shfl_xor((int)wA, 32);
        unsigned tB = (unsigned)__shfl_xor((int)wB, 32);
        unsigned tC = (unsigned)__shfl_xor((int)wC, 32);
        unsigned tD = (unsigned)__shfl_xor((int)wD, 32);
        union { unsigned u[4]; bf16x8 v; } pk;
        pk.u[0] = hh ? tB : wA;       // kv 16(2i+s) + 8hh + {0,1}
        pk.u[1] = hh ? tD : wC;       //                  + {2,3}
        pk.u[2] = hh ? wB : tA;       //                  + {4,5}
        pk.u[3] = hh ? wD : tC;       //                  + {6,7}
        pb[2 * i + s] = pk.v;
      }

    // ---- prefetch V for dt=2,3 (hides under PV dt0-1) ----
    bf16x8 vf1[8];
#pragma unroll
    for (int dt = 0; dt < 2; ++dt)
#pragma unroll
      for (int ks = 0; ks < 4; ++ks)
        vf1[4 * dt + ks] = *(const bf16x8*)(Vh + (size_t)(64 + 32 * dt + ql) * S_ + kt + ks * 16 + hh * 8);

    // ---- PV: O^T[d 128][q 32] += V^T(128x64) @ P^T(64x32) ----
    __builtin_amdgcn_s_setprio(1);
#pragma unroll
    for (int dt = 0; dt < 2; ++dt)
#pragma unroll
      for (int ks = 0; ks < 4; ++ks)
        o[dt] = __builtin_amdgcn_mfma_f32_32x32x16_bf16(vf0[4 * dt + ks], pb[ks], o[dt], 0, 0, 0);
#pragma unroll
    for (int dt = 0; dt < 2; ++dt)
#pragma unroll
      for (int ks = 0; ks < 4; ++ks)
        o[2 + dt] = __builtin_amdgcn_mfma_f32_32x32x16_bf16(vf1[4 * dt + ks], pb[ks], o[2 + dt], 0, 0, 0);
    __builtin_amdgcn_s_setprio(0);
  };

  loadK(kA, 0);
  for (int t = 0; t < nt; ++t) {
    if (t & 1) body(kB, kA, t);
    else       body(kA, kB, t);
  }

  // ---- epilogue: O^T -> AO[b][q][h*128+d], per-lane normalize ----
  const float inv = 1.f / l;
#pragma unroll
  for (int dt = 0; dt < 4; ++dt)
#pragma unroll
    for (int g = 0; g < 4; ++g) {
      u16x4 pk4;
#pragma unroll
      for (int e = 0; e < 4; ++e) pk4[e] = f2bf(o[dt][4 * g + e] * inv);
      *(u16x4*)(AO + ((size_t)b * S_ + qg) * HID_ + h * HD_ + 32 * dt + 8 * g + 4 * hh) = pk4;
    }
}

// ---------------- launcher --------------------------------------------------
extern "C" void kernel_launch(void* const* d_in, const int* in_sizes, int n_in,
                              void* d_out, int out_size, void* d_ws, size_t ws_size,
                              hipStream_t stream)
{
  (void)in_sizes; (void)n_in; (void)out_size; (void)ws_size;
  const float* X  = (const float*)d_in[0];
  const float* fc = (const float*)d_in[1];
  const float* fs = (const float*)d_in[2];
  // d_in[3] attention_mask: fixed causal mask, implemented analytically
  const float* Wq = (const float*)d_in[4];
  const float* Wk = (const float*)d_in[5];
  const float* Wv = (const float*)d_in[6];
  const float* Wo = (const float*)d_in[7];
  float* out = (float*)d_out;

  u16* Xb  = (u16*)d_ws;                        // 8M elems (reused as AO)
  u16* Wb  = Xb + (size_t)4096 * 2048;          // 3072x2048 (reused: Wob + Vtg)
  u16* Qb  = Wb + (size_t)3072 * 2048;          // 8M
  u16* Kb  = Qb + (size_t)B_ * NH_ * S_ * HD_;  // 2M
  u16* Vb  = Kb + (size_t)B_ * NKV_ * S_ * HD_; // 2M
  u16* AO  = Xb;
  u16* Wob = Wb;                                // 4M elems
  u16* Vtg = Wb + (size_t)2048 * 2048;          // 2M elems (spare tail of Wb)

  // bf16 conversions
  convert_bf16<<<4096, 256, 0, stream>>>(X,  Xb,               4096 * 2048 / 8);
  convert_bf16<<<2048, 256, 0, stream>>>(Wq, Wb,               2048 * 2048 / 8);
  convert_bf16<<<512,  256, 0, stream>>>(Wk, Wb + 2048 * 2048, 512 * 2048 / 8);
  convert_bf16<<<512,  256, 0, stream>>>(Wv, Wb + 2560 * 2048, 512 * 2048 / 8);

  // QKV projection with scatter epilogue
  gemm128<1><<<dim3(32, 24), 256, 0, stream>>>(Xb, Wb, nullptr, Qb, Kb, Vb, 3072, 2048);

  // Wo conversion (reuses Wb[0:4M], dead after gemm1)
  convert_bf16<<<2048, 256, 0, stream>>>(Wo, Wob, 2048 * 2048 / 8);

  // V transpose into Vtg [hs][128][2048] (Wb spare tail, dead after gemm1)
  transpose_v<<<dim3(32, 2, 8), 256, 0, stream>>>(Vb, Vtg);

  // RoPE in place on Q and K
  rope_k<<<5120, 256, 0, stream>>>(Qb, Kb, fc, fs);

  // causal flash attention -> AO (aliases Xb, dead after gemm1)
  flash_attn<<<dim3(16, NH_, B_), 256, 0, stream>>>(Qb, Kb, Vtg, AO);

  // output projection -> fp32 d_out
  gemm128<0><<<dim3(32, 16), 256, 0, stream>>>(AO, Wob, out, nullptr, nullptr, nullptr, 2048, 2048);
}

// Round 8
// 233.495 us; speedup vs baseline: 2.7773x; 2.7773x over previous
//
#include <hip/hip_runtime.h>

// GQA forward: X@Wq/Wk/Wv -> RoPE -> causal flash attention -> @Wo
// B=2 S=2048 HID=2048 NH=16 NKV=4 HD=128 GROUPS=4

typedef __attribute__((ext_vector_type(8))) short bf16x8;
typedef __attribute__((ext_vector_type(4))) float f32x4;
typedef __attribute__((ext_vector_type(16))) float f32x16;
typedef __attribute__((ext_vector_type(4))) unsigned short u16x4;
typedef unsigned short u16;

#define B_   2
#define S_   2048
#define HID_ 2048
#define NH_  16
#define NKV_ 4
#define HD_  128

__device__ __forceinline__ u16 f2bf(float f) {
  unsigned u = __float_as_uint(f);
  u = (u + 0x7FFFu + ((u >> 16) & 1u)) >> 16;
  return (u16)u;
}
__device__ __forceinline__ float bf2f(u16 h) {
  return __uint_as_float(((unsigned)h) << 16);
}

__device__ __forceinline__ void gl_lds16(const void* g, void* l) {
  __builtin_amdgcn_global_load_lds(
      (const __attribute__((address_space(1))) void*)g,
      (__attribute__((address_space(3))) void*)l, 16, 0, 0);
}

// ---------------- fp32 -> bf16 conversion (vectorized, 8 elems/thread) ------
__global__ void convert_bf16(const float* __restrict__ src, u16* __restrict__ dst, int n8) {
  int i = blockIdx.x * 256 + threadIdx.x;
  if (i >= n8) return;
  const float4* s = (const float4*)src + (size_t)i * 2;
  float4 a = s[0], b = s[1];
  union { u16 u[8]; uint4 v; } o;
  o.u[0] = f2bf(a.x); o.u[1] = f2bf(a.y); o.u[2] = f2bf(a.z); o.u[3] = f2bf(a.w);
  o.u[4] = f2bf(b.x); o.u[5] = f2bf(b.y); o.u[6] = f2bf(b.z); o.u[7] = f2bf(b.w);
  ((uint4*)dst)[i] = o.v;
}

// ---------------- 128x128 bf16 GEMM, C = A @ B^T (m97 structure) -----------
template<int EPI>
__launch_bounds__(256, 2)
__global__ void gemm128(const u16* __restrict__ A, const u16* __restrict__ Bm,
                        float* __restrict__ C, u16* __restrict__ Qb,
                        u16* __restrict__ Kb, u16* __restrict__ Vb,
                        int N, int K)
{
  __shared__ u16 As[128 * 64];
  __shared__ u16 Bs[128 * 64];
  const int tid = threadIdx.x;
  const int lane = tid & 63;
  const int w = tid >> 6;
  const int lo = lane & 15, hi = lane >> 4;
  const int wr = w >> 1, wc = w & 1;
  const int rowA0 = blockIdx.x * 128;
  const int rowB0 = blockIdx.y * 128;

  f32x4 acc[4][4] = {};

  for (int kt = 0; kt < K; kt += 64) {
    __syncthreads();
#pragma unroll
    for (int it = 0; it < 4; ++it) {
      int c = it * 256 + tid;       // 16B chunk; row = c>>3, 8 chunks/row
      int r = c >> 3;
      int cb = (c & 7) * 8;
      gl_lds16(A + (size_t)(rowA0 + r) * K + kt + cb, (char*)As + c * 16);
      gl_lds16(Bm + (size_t)(rowB0 + r) * K + kt + cb, (char*)Bs + c * 16);
    }
    __syncthreads();
#pragma unroll
    for (int kk = 0; kk < 64; kk += 32) {
      bf16x8 af[4], bfr[4];
#pragma unroll
      for (int m = 0; m < 4; ++m)
        af[m] = *(const bf16x8*)(As + (wr * 64 + m * 16 + lo) * 64 + kk + hi * 8);
#pragma unroll
      for (int n = 0; n < 4; ++n)
        bfr[n] = *(const bf16x8*)(Bs + (wc * 64 + n * 16 + lo) * 64 + kk + hi * 8);
#pragma unroll
      for (int m = 0; m < 4; ++m)
#pragma unroll
        for (int n = 0; n < 4; ++n)
          acc[m][n] = __builtin_amdgcn_mfma_f32_16x16x32_bf16(af[m], bfr[n], acc[m][n], 0, 0, 0);
    }
  }

#pragma unroll
  for (int m = 0; m < 4; ++m) {
#pragma unroll
    for (int n = 0; n < 4; ++n) {
#pragma unroll
      for (int r = 0; r < 4; ++r) {
        int grow = rowA0 + wr * 64 + m * 16 + hi * 4 + r;
        int gcol = rowB0 + wc * 64 + n * 16 + lo;
        float v = acc[m][n][r];
        if (EPI == 0) {
          C[(size_t)grow * N + gcol] = v;
        } else {
          int bb = grow >> 11, s = grow & 2047;
          u16 hv = f2bf(v);
          if (gcol < 2048) {
            int h = gcol >> 7, d = gcol & 127;
            Qb[(((size_t)bb * NH_ + h) * S_ + s) * HD_ + d] = hv;
          } else if (gcol < 2560) {
            int h = (gcol - 2048) >> 7, d = gcol & 127;
            Kb[(((size_t)bb * NKV_ + h) * S_ + s) * HD_ + d] = hv;
          } else {
            int h = (gcol - 2560) >> 7, d = gcol & 127;
            Vb[(((size_t)bb * NKV_ + h) * S_ + s) * HD_ + d] = hv;
          }
        }
      }
    }
  }
}

// ---------------- in-place RoPE on Qb and Kb (bf16) -------------------------
__global__ void rope_k(u16* __restrict__ Qb, u16* __restrict__ Kb,
                       const float* __restrict__ fcos, const float* __restrict__ fsin)
{
  int idx = blockIdx.x * 256 + threadIdx.x;   // 40*2048*16 chunks total
  int chunk = idx & 15;
  int s = (idx >> 4) & 2047;
  int hs = idx >> 15;                          // 0..39
  u16* p = (hs < 32) ? (Qb + ((size_t)hs * S_ + s) * HD_ + chunk * 8)
                     : (Kb + ((size_t)(hs - 32) * S_ + s) * HD_ + chunk * 8);
  uint4 raw = *(uint4*)p;
  float4 c4 = *(const float4*)(fcos + (size_t)s * 64 + chunk * 4);
  float4 s4 = *(const float4*)(fsin + (size_t)s * 64 + chunk * 4);
  float cc[4] = {c4.x, c4.y, c4.z, c4.w};
  float ss[4] = {s4.x, s4.y, s4.z, s4.w};
  unsigned* rw = (unsigned*)&raw;
#pragma unroll
  for (int j = 0; j < 4; ++j) {
    float x0 = bf2f((u16)(rw[j] & 0xFFFFu));
    float x1 = bf2f((u16)(rw[j] >> 16));
    float o0 = x0 * cc[j] - x1 * ss[j];
    float o1 = x0 * ss[j] + x1 * cc[j];
    rw[j] = (unsigned)f2bf(o0) | ((unsigned)f2bf(o1) << 16);
  }
  *(uint4*)p = raw;
}

// ---------------- V transpose: Vb [hs][s][d] -> Vtg [hs][d][s] -------------
__global__ void transpose_v(const u16* __restrict__ Vb, u16* __restrict__ Vtg)
{
  __shared__ u16 t[64][65];
  const int st = blockIdx.x, dt = blockIdx.y, hs = blockIdx.z;
  const u16* src = Vb + ((size_t)hs * S_ + st * 64) * HD_ + dt * 64;
#pragma unroll
  for (int it = 0; it < 2; ++it) {
    int c = it * 256 + threadIdx.x;
    int r = c >> 3, cb = (c & 7) * 8;
    uint4 v = *(const uint4*)(src + (size_t)r * HD_ + cb);
    u16* u = (u16*)&v;
#pragma unroll
    for (int e = 0; e < 8; ++e) t[r][cb + e] = u[e];
  }
  __syncthreads();
#pragma unroll
  for (int it = 0; it < 2; ++it) {
    int c = it * 256 + threadIdx.x;
    int r2 = c >> 3, cb2 = (c & 7) * 8;
    union { u16 u[8]; uint4 v; } o;
#pragma unroll
    for (int e = 0; e < 8; ++e) o.u[e] = t[cb2 + e][r2];
    *(uint4*)(Vtg + ((size_t)hs * HD_ + dt * 64 + r2) * S_ + st * 64 + cb2) = o.v;
  }
}

// ---------------- causal flash attention ------------------------------------
// 4-wave / 256-thread blocks; waves own SCATTERED 32-row q-tiles
// {x, 63-x, 31-x, 32+x} sharing the block's staged K/V tiles: compute per
// block uniform (66 wave-tiles), staging loop bnt = 25..32 tiles.
// Grid = 512 linear blocks = 2 blocks/CU = 2048 waves = 2 waves/SIMD ->
// one block's stage-drain overlaps the other's compute (m114).
// XCD decode: HW block i -> XCD i%8; g=lin&7 -> (b,kvh): each XCD works on
// exactly ONE 2MB KV set -> L2-resident with maximal reuse.
// LDS 64KB/block double-buffered; both-sides swizzle sw(r)=(r&7)^((r>>3)&3).
// Math identical to validated R5/R6 body (swapped 32x32 QK/PV, defer-max).
__launch_bounds__(256, 2)
__global__ void flash_attn(const u16* __restrict__ Qb, const u16* __restrict__ Kb,
                           const u16* __restrict__ Vtg, u16* __restrict__ AO)
{
  __shared__ u16 Ks[2][64 * 128];   // [kv][d], 16 slots/row
  __shared__ u16 Vt[2][128 * 64];   // [d][kv], 8 slots/row

  const int tid = threadIdx.x, lane = tid & 63, w = tid >> 6;  // w in 0..3
  const int ql = lane & 31, hh = lane >> 5;
  const int swl = (ql & 7) ^ ((ql >> 3) & 3);   // read-side swizzle

  const int lin = blockIdx.x;                   // 0..511
  const int g = lin & 7, idx = lin >> 3;        // XCD group g owns one (b,kvh)
  const int b = g >> 2, kvh = g & 3;
  const int h = kvh * 4 + (idx >> 4);           // h>>2 == kvh
  const int x = idx & 15;                       // 0..15

  const u16* Qh = Qb + ((size_t)b * NH_ + h) * S_ * HD_;
  const u16* Kh = Kb + ((size_t)b * NKV_ + kvh) * S_ * HD_;
  const u16* Vh = Vtg + ((size_t)b * NKV_ + kvh) * HD_ * S_;
  const float cf = 0.12752704581383682f;  // (1/sqrt(128)) * log2(e)
  const float NEG = -30000.f;

  // per-wave q-tile: {x, 63-x, 31-x, 32+x} -> uniform block compute
  const int qt = (w == 0) ? x : (w == 1) ? (63 - x) : (w == 2) ? (31 - x) : (32 + x);
  const int q0 = qt * 32;
  const int qg = q0 + ql;                       // this lane's q row
  const int bnt = ((63 - x) >> 1) + 1;          // block staging tiles (max wave nt)

  auto STAGE = [&](int buf, int kt) {
#pragma unroll
    for (int it = 0; it < 4; ++it) {            // K: 64 rows x 16 slots
      int c = it * 256 + tid;
      int r = c >> 4;
      int slot = (c & 15) ^ (r & 7) ^ ((r >> 3) & 3);
      gl_lds16(Kh + (size_t)(kt + r) * HD_ + slot * 8, (char*)Ks[buf] + c * 16);
    }
#pragma unroll
    for (int it = 0; it < 4; ++it) {            // V^T: 128 rows x 8 slots
      int c = it * 256 + tid;
      int r = c >> 3;
      int slot = (c & 7) ^ ((r & 7) ^ ((r >> 3) & 3));
      gl_lds16(Vh + (size_t)r * S_ + kt + slot * 8, (char*)Vt[buf] + c * 16);
    }
  };

  bf16x8 qf[8];
#pragma unroll
  for (int s = 0; s < 8; ++s)
    qf[s] = *(const bf16x8*)(Qh + (size_t)qg * HD_ + s * 16 + hh * 8);

  f32x16 o[4] = {};
  float m = NEG, l = 0.f;

  STAGE(0, 0);
  __syncthreads();                              // compiler drains vmcnt here
  int cur = 0;

  for (int t = 0; t < bnt; ++t) {
    if (t + 1 < bnt) STAGE(cur ^ 1, (t + 1) * 64);   // prefetch next tile
    const int kt = t * 64;
    if (kt < q0 + 32) {                          // wave-uniform causal predicate
      // ---- QK^T: S^T[kv 64][q 32], 16 mfma ----
      f32x16 st[2] = {};
      __builtin_amdgcn_s_setprio(1);
#pragma unroll
      for (int sl = 0; sl < 8; ++sl) {
        int slot = ((2 * sl + hh) ^ swl) * 16;
        bf16x8 k0 = *(const bf16x8*)((const char*)Ks[cur] + ql * 256 + slot);
        bf16x8 k1 = *(const bf16x8*)((const char*)Ks[cur] + (32 + ql) * 256 + slot);
        st[0] = __builtin_amdgcn_mfma_f32_32x32x16_bf16(k0, qf[sl], st[0], 0, 0, 0);
        st[1] = __builtin_amdgcn_mfma_f32_32x32x16_bf16(k1, qf[sl], st[1], 0, 0, 0);
      }
      __builtin_amdgcn_s_setprio(0);

      // ---- mask (tiles overlapping the diagonal) ----
      if ((kt + 63) > q0) {
#pragma unroll
        for (int i = 0; i < 2; ++i)
#pragma unroll
          for (int r = 0; r < 16; ++r) {
            int kv = kt + 32 * i + (r & 3) + 8 * (r >> 2) + 4 * hh;
            if (kv > qg) st[i][r] = NEG;
          }
      }

      // ---- row max: in-lane tree + cross-half shfl ----
      float mx[8];
#pragma unroll
      for (int r = 0; r < 8; ++r)
        mx[r] = fmaxf(fmaxf(st[0][r], st[0][r + 8]), fmaxf(st[1][r], st[1][r + 8]));
#pragma unroll
      for (int d = 4; d > 0; d >>= 1)
#pragma unroll
        for (int r = 0; r < d; ++r) mx[r] = fmaxf(mx[r], mx[r + d]);
      float tmax = fmaxf(mx[0], __shfl_xor(mx[0], 32));

      // ---- defer-max (T13): rescale only when max grew materially ----
      if (!__all((tmax - m) * cf <= 8.f)) {
        float mn = fmaxf(m, tmax);
        float rs = __builtin_exp2f((m - mn) * cf);
        m = mn; l *= rs;
#pragma unroll
        for (int dt = 0; dt < 4; ++dt)
#pragma unroll
          for (int r = 0; r < 16; ++r) o[dt][r] *= rs;
      }

      // ---- exp2 + row sum ----
      const float mc = m * cf;
#pragma unroll
      for (int i = 0; i < 2; ++i)
#pragma unroll
        for (int r = 0; r < 16; ++r)
          st[i][r] = __builtin_exp2f(__builtin_fmaf(st[i][r], cf, -mc));
      float sm[8];
#pragma unroll
      for (int r = 0; r < 8; ++r)
        sm[r] = (st[0][r] + st[0][r + 8]) + (st[1][r] + st[1][r + 8]);
#pragma unroll
      for (int d = 4; d > 0; d >>= 1)
#pragma unroll
        for (int r = 0; r < d; ++r) sm[r] += sm[r + d];
      l += sm[0] + __shfl_xor(sm[0], 32);

      // ---- P -> PV B-frag: cvt_pk + cross-half shfl exchange ----
      bf16x8 pb[4];
#pragma unroll
      for (int i = 0; i < 2; ++i)
#pragma unroll
        for (int s = 0; s < 2; ++s) {
          unsigned wA, wC, wB, wD;
          asm("v_cvt_pk_bf16_f32 %0, %1, %2" : "=v"(wA) : "v"(st[i][8*s+0]), "v"(st[i][8*s+1]));
          asm("v_cvt_pk_bf16_f32 %0, %1, %2" : "=v"(wC) : "v"(st[i][8*s+2]), "v"(st[i][8*s+3]));
          asm("v_cvt_pk_bf16_f32 %0, %1, %2" : "=v"(wB) : "v"(st[i][8*s+4]), "v"(st[i][8*s+5]));
          asm("v_cvt_pk_bf16_f32 %0, %1, %2" : "=v"(wD) : "v"(st[i][8*s+6]), "v"(st[i][8*s+7]));
          unsigned tA = (unsigned)__shfl_xor((int)wA, 32);
          unsigned tB = (unsigned)__shfl_xor((int)wB, 32);
          unsigned tC = (unsigned)__shfl_xor((int)wC, 32);
          unsigned tD = (unsigned)__shfl_xor((int)wD, 32);
          union { unsigned u[4]; bf16x8 v; } pk;
          pk.u[0] = hh ? tB : wA;       // kv 16(2i+s) + 8hh + {0,1}
          pk.u[1] = hh ? tD : wC;       //                  + {2,3}
          pk.u[2] = hh ? wB : tA;       //                  + {4,5}
          pk.u[3] = hh ? wD : tC;       //                  + {6,7}
          pb[2 * i + s] = pk.v;
        }

      // ---- PV: O^T[d 128][q 32] += V^T(128x64) @ P^T(64x32), 16 mfma ----
      __builtin_amdgcn_s_setprio(1);
#pragma unroll
      for (int dt = 0; dt < 4; ++dt)
#pragma unroll
        for (int ks = 0; ks < 4; ++ks) {
          int row = 32 * dt + ql;
          bf16x8 vf = *(const bf16x8*)((const char*)Vt[cur] + row * 128 +
                                       (((2 * ks + hh) ^ swl) & 7) * 16);
          o[dt] = __builtin_amdgcn_mfma_f32_32x32x16_bf16(vf, pb[ks], o[dt], 0, 0, 0);
        }
      __builtin_amdgcn_s_setprio(0);
    }
    __syncthreads();                    // drains vmcnt+lgkm: prefetch landed
    cur ^= 1;
  }

  // ---- epilogue: O^T -> AO[b][q][h*128+d], per-lane normalize ----
  const float inv = 1.f / l;
#pragma unroll
  for (int dt = 0; dt < 4; ++dt)
#pragma unroll
    for (int gi = 0; gi < 4; ++gi) {
      u16x4 pk4;
#pragma unroll
      for (int e = 0; e < 4; ++e) pk4[e] = f2bf(o[dt][4 * gi + e] * inv);
      *(u16x4*)(AO + ((size_t)b * S_ + qg) * HID_ + h * HD_ + 32 * dt + 8 * gi + 4 * hh) = pk4;
    }
}

// ---------------- launcher --------------------------------------------------
extern "C" void kernel_launch(void* const* d_in, const int* in_sizes, int n_in,
                              void* d_out, int out_size, void* d_ws, size_t ws_size,
                              hipStream_t stream)
{
  (void)in_sizes; (void)n_in; (void)out_size; (void)ws_size;
  const float* X  = (const float*)d_in[0];
  const float* fc = (const float*)d_in[1];
  const float* fs = (const float*)d_in[2];
  // d_in[3] attention_mask: fixed causal mask, implemented analytically
  const float* Wq = (const float*)d_in[4];
  const float* Wk = (const float*)d_in[5];
  const float* Wv = (const float*)d_in[6];
  const float* Wo = (const float*)d_in[7];
  float* out = (float*)d_out;

  u16* Xb  = (u16*)d_ws;                        // 8M elems (reused as AO)
  u16* Wb  = Xb + (size_t)4096 * 2048;          // 3072x2048 (reused: Wob + Vtg)
  u16* Qb  = Wb + (size_t)3072 * 2048;          // 8M
  u16* Kb  = Qb + (size_t)B_ * NH_ * S_ * HD_;  // 2M
  u16* Vb  = Kb + (size_t)B_ * NKV_ * S_ * HD_; // 2M
  u16* AO  = Xb;
  u16* Wob = Wb;                                // 4M elems
  u16* Vtg = Wb + (size_t)2048 * 2048;          // 2M elems (spare tail of Wb)

  // bf16 conversions
  convert_bf16<<<4096, 256, 0, stream>>>(X,  Xb,               4096 * 2048 / 8);
  convert_bf16<<<2048, 256, 0, stream>>>(Wq, Wb,               2048 * 2048 / 8);
  convert_bf16<<<512,  256, 0, stream>>>(Wk, Wb + 2048 * 2048, 512 * 2048 / 8);
  convert_bf16<<<512,  256, 0, stream>>>(Wv, Wb + 2560 * 2048, 512 * 2048 / 8);

  // QKV projection with scatter epilogue
  gemm128<1><<<dim3(32, 24), 256, 0, stream>>>(Xb, Wb, nullptr, Qb, Kb, Vb, 3072, 2048);

  // Wo conversion (reuses Wb[0:4M], dead after gemm1)
  convert_bf16<<<2048, 256, 0, stream>>>(Wo, Wob, 2048 * 2048 / 8);

  // V transpose into Vtg [hs][128][2048] (Wb spare tail, dead after gemm1)
  transpose_v<<<dim3(32, 2, 8), 256, 0, stream>>>(Vb, Vtg);

  // RoPE in place on Q and K
  rope_k<<<5120, 256, 0, stream>>>(Qb, Kb, fc, fs);

  // causal flash attention -> AO (aliases Xb, dead after gemm1)
  flash_attn<<<512, 256, 0, stream>>>(Qb, Kb, Vtg, AO);

  // output projection -> fp32 d_out
  gemm128<0><<<dim3(32, 16), 256, 0, stream>>>(AO, Wob, out, nullptr, nullptr, nullptr, 2048, 2048);
}